// Round 2
// baseline (106.862 us; speedup 1.0000x reference)
//
#include <hip/hip_runtime.h>
#include <hip/hip_bf16.h>
#include <stdint.h>

typedef short bf16x8 __attribute__((ext_vector_type(8)));
typedef float f32x4 __attribute__((ext_vector_type(4)));

#define DEVI static __device__ __forceinline__

constexpr int B_   = 32768;
constexpr int IN_  = 128;
constexpr int LF_  = 512;
constexpr int OUT_ = 32;

// ---- workspace layout (bytes) ----
// All B-side matrices stored in MFMA-fragment order:
//   chunk(tile,kstep) at base + chunk*64*16B; lane ln reads +ln*16B (coalesced).
// Fragment content for lane ln: row n = tile*16 + (ln&15), k = kstep*32 + (ln>>4)*8 .. +7.
constexpr size_t OFF_LTF = 0;                    // 32 tiles x 16 ks x 1KB = 524,288
constexpr size_t OFF_W1F = 524288;               // 32 tiles x 4 ks x 1KB  = 131,072
constexpr size_t OFF_W2F = OFF_W1F + 131072;     // 3 tiles x 16 ks x 1KB  = 49,152

DEVI short f2bs(float f) { __hip_bfloat16 h = __float2bfloat16(f); return *(short*)&h; }

// fast tanh: 1 - 2/(e^{2v}+1)
DEVI float tanh_fast(float v) {
    float e = __expf(2.0f * v);
    return 1.0f - 2.0f * __builtin_amdgcn_rcpf(e + 1.0f);
}

// coalesced fragment load: chunk = tile*ksteps + ks
DEVI bf16x8 fragGL(const __hip_bfloat16* base, int chunk, int ln) {
    return *(const bf16x8*)(base + ((size_t)chunk * 64 + ln) * 8);
}

// phi LDS tile: 32 rows x 64 chunks(16B); slot = row*64 + ((k>>3) ^ (row&7))
DEVI bf16x8 phiFrag(const char* p, int row, int kofs) {
    int c = (kofs >> 3) ^ (row & 7);
    return *(const bf16x8*)(p + (size_t)((row << 6) + c) * 16);
}
DEVI void phiStore(char* p, int row, int col, float v) {
    int c = (col >> 3) ^ (row & 7);
    *(short*)(p + (size_t)((row << 6) + c) * 16 + (col & 7) * 2) = f2bs(v);
}
// x LDS tile: 32 rows x 16 chunks; slot = row*16 + ((k>>3) ^ (row&15))
DEVI bf16x8 xFrag(const char* p, int row, int kofs) {
    int c = (kofs >> 3) ^ (row & 15);
    return *(const bf16x8*)(p + (size_t)((row << 4) + c) * 16);
}

// ---------------- prep: build fragment-order W1F / W2F / LTF ----------------
// one thread per 16B chunk: 8192 (w1f) + 3072 (w2f) + 32768 (ltf) = 44032
__global__ __launch_bounds__(256) void k_prep(
        const float* __restrict__ w1, const float* __restrict__ w2,
        const float* __restrict__ lv, const float* __restrict__ qb,
        __hip_bfloat16* __restrict__ w1f, __hip_bfloat16* __restrict__ w2f,
        __hip_bfloat16* __restrict__ ltf) {
    int cid = blockIdx.x * 256 + threadIdx.x;
    if (cid < 8192) {                       // W1F: nt(32) x ks(4) x ln(64)
        int ln = cid & 63, ks = (cid >> 6) & 3, nt = cid >> 8;
        int n = nt * 16 + (ln & 15), kb = ks * 32 + (ln >> 4) * 8;
        const float* src = w1 + (size_t)n * IN_ + kb;
        bf16x8 o;
#pragma unroll
        for (int i = 0; i < 8; ++i) o[i] = f2bs(src[i]);
        *(bf16x8*)(w1f + (size_t)cid * 8) = o;
    } else if (cid < 11264) {               // W2F: nt(3) x ks(16) x ln(64)
        int c2 = cid - 8192;
        int ln = c2 & 63, ks = (c2 >> 6) & 15, nt = c2 >> 10;
        int n = nt * 16 + (ln & 15), kb = ks * 32 + (ln >> 4) * 8;
        bf16x8 o;
#pragma unroll
        for (int i = 0; i < 8; ++i) {
            float v = (n < OUT_) ? w2[(size_t)n * LF_ + kb + i]
                                 : (n == OUT_ ? qb[kb + i] : 0.f);
            o[i] = f2bs(v);
        }
        *(bf16x8*)(w2f + (size_t)c2 * 8) = o;
    } else if (cid < 44032) {               // LTF: t(32) x ks(16) x ln(64)
        int c3 = cid - 11264;
        int ln = c3 & 63, ks = (c3 >> 6) & 15, t = c3 >> 10;
        int j = t * 16 + (ln & 15), kb = ks * 32 + (ln >> 4) * 8;
        bf16x8 o;
#pragma unroll
        for (int i = 0; i < 8; ++i) {
            int k = kb + i;                 // Lt[j][k] = L[k][j], zero for k<j
            o[i] = (k >= j) ? f2bs(lv[(size_t)k * (k + 1) / 2 + j]) : (short)0;
        }
        *(bf16x8*)(ltf + (size_t)c3 * 8) = o;
    }
}

// ---------------- fused: x->phi(LDS)->pi,vf ----------------
// M=32 rows/block, 512 threads (8 waves). Per-wave accumulator footprint is
// HALVED vs the M=64 version (acc = 32 f32 in every phase) so the hot loops
// fit well inside the 128-VGPR budget implied by (512,4) -> no scratch spills.
// LDS: phi 32KB | stage 8KB (x, then vfb/vfp alias) = 40KB -> 2 blocks/CU.
__global__ __launch_bounds__(512, 4) void k_fused(
        const float* __restrict__ x, const __hip_bfloat16* __restrict__ w1f,
        const float* __restrict__ b1, const __hip_bfloat16* __restrict__ w2f,
        const __hip_bfloat16* __restrict__ ltf, const float* __restrict__ qcp,
        float* __restrict__ pi, float* __restrict__ vf) {
    __shared__ char smem[40960];
    char*  phiB  = smem;
    char*  stage = smem + 32768;
    float* vfb   = (float*)stage;          // 32 f32 (alias; valid after phase-1 barrier)
    float* vfp   = (float*)(stage + 256);  // 8x32 f32

    const int tid = threadIdx.x, wv = tid >> 6, ln = tid & 63;
    const int cl = ln & 15, q = ln >> 4;
    const int m0 = blockIdx.x * 32;

    // ---- phase 0: load+cast x tile (32x128 fp32 -> bf16) into LDS; 1 chunk/thread ----
    {
        int row = tid >> 4, cg = tid & 15;
        const float4* p = (const float4*)(x + (size_t)(m0 + row) * IN_ + cg * 8);
        float4 u0 = p[0], u1 = p[1];
        bf16x8 pk;
        pk[0] = f2bs(u0.x); pk[1] = f2bs(u0.y); pk[2] = f2bs(u0.z); pk[3] = f2bs(u0.w);
        pk[4] = f2bs(u1.x); pk[5] = f2bs(u1.y); pk[6] = f2bs(u1.z); pk[7] = f2bs(u1.w);
        *(bf16x8*)(stage + (size_t)((row << 4) + (cg ^ (row & 15))) * 16) = pk;
    }
    __syncthreads();

    // ---- phase 1: phi = tanh(x @ W1^T + b1); wave owns 64-col strip x 32 rows ----
    {
        f32x4 acc[2][4] = {};   // 32 VGPRs
#pragma unroll
        for (int ks = 0; ks < 4; ++ks) {
            bf16x8 a[2], bfr[4];
#pragma unroll
            for (int mi = 0; mi < 2; ++mi) a[mi] = xFrag(stage, mi * 16 + cl, ks * 32 + q * 8);
#pragma unroll
            for (int ni = 0; ni < 4; ++ni)
                bfr[ni] = fragGL(w1f, (4 * wv + ni) * 4 + ks, ln);
#pragma unroll
            for (int mi = 0; mi < 2; ++mi)
#pragma unroll
                for (int ni = 0; ni < 4; ++ni)
                    acc[mi][ni] = __builtin_amdgcn_mfma_f32_16x16x32_bf16(
                        a[mi], bfr[ni], acc[mi][ni], 0, 0, 0);
        }
#pragma unroll
        for (int ni = 0; ni < 4; ++ni) {
            int colg = wv * 64 + ni * 16 + cl;
            float bv = b1[colg];
#pragma unroll
            for (int mi = 0; mi < 2; ++mi)
#pragma unroll
                for (int r = 0; r < 4; ++r)
                    phiStore(phiB, mi * 16 + q * 4 + r, colg,
                             tanh_fast(acc[mi][ni][r] + bv));
        }
    }
    __syncthreads();   // phi complete; x/stage dead -> vfb/vfp alias valid

    // ---- phase 2: pi = phi @ W2ext^T; 6 (mi,ni) wave-tiles, waves 0-5 ----
    // two independent MFMA chains (even/odd ks) halve the dependent-accumulate
    // latency of the 16-step K loop; summed at the end.
    if (wv < 6) {
        int mi = wv & 1, ni = wv >> 1;
        f32x4 a2a = {}, a2b = {};
#pragma unroll
        for (int ks = 0; ks < 16; ks += 2) {
            bf16x8 ae = phiFrag(phiB, mi * 16 + cl, ks * 32 + q * 8);
            bf16x8 be = fragGL(w2f, ni * 16 + ks, ln);
            a2a = __builtin_amdgcn_mfma_f32_16x16x32_bf16(ae, be, a2a, 0, 0, 0);
            bf16x8 ao = phiFrag(phiB, mi * 16 + cl, (ks + 1) * 32 + q * 8);
            bf16x8 bo = fragGL(w2f, ni * 16 + ks + 1, ln);
            a2b = __builtin_amdgcn_mfma_f32_16x16x32_bf16(ao, bo, a2b, 0, 0, 0);
        }
        f32x4 a2 = a2a + a2b;
#pragma unroll
        for (int r = 0; r < 4; ++r) {
            int row = mi * 16 + q * 4 + r, col = ni * 16 + cl;
            if (col < OUT_)       pi[(size_t)(m0 + row) * OUT_ + col] = a2[r];
            else if (col == OUT_) vfb[row] = a2[r];   // phi.qb
        }
    }

    // ---- phase 3: y = rowsum((phi @ L)^2); mirrored tiles, prefetched B ----
    {
        int tl[4] = { wv, 15 - wv, 16 + wv, 31 - wv };
        int kstart[4];
#pragma unroll
        for (int j = 0; j < 4; ++j) kstart[j] = (tl[j] * 16) & ~31;  // exact: Lt zero-padded
        int kmin = kstart[0];            // tl[0] is the smallest tile index
        f32x4 acc[4][2] = {};            // 32 VGPRs
        bf16x8 bcur[4];
#pragma unroll
        for (int j = 0; j < 4; ++j)      // Lt zero-filled below diag: loads always valid
            bcur[j] = fragGL(ltf, tl[j] * 16 + (kmin >> 5), ln);
        for (int k0 = kmin; k0 < LF_; k0 += 32) {
            bf16x8 a0 = phiFrag(phiB, cl,      k0 + q * 8);
            bf16x8 a1 = phiFrag(phiB, 16 + cl, k0 + q * 8);
            int kf = (k0 + 32 < LF_) ? (k0 + 32) : k0;   // clamped prefetch
            bf16x8 bnx[4];
#pragma unroll
            for (int j = 0; j < 4; ++j)
                bnx[j] = fragGL(ltf, tl[j] * 16 + (kf >> 5), ln);
#pragma unroll
            for (int j = 0; j < 4; ++j) {
                if (k0 >= kstart[j]) {          // wave-uniform branch
                    acc[j][0] = __builtin_amdgcn_mfma_f32_16x16x32_bf16(
                        a0, bcur[j], acc[j][0], 0, 0, 0);
                    acc[j][1] = __builtin_amdgcn_mfma_f32_16x16x32_bf16(
                        a1, bcur[j], acc[j][1], 0, 0, 0);
                }
            }
#pragma unroll
            for (int j = 0; j < 4; ++j) bcur[j] = bnx[j];
        }
        float vacc[2][4];
#pragma unroll
        for (int mi = 0; mi < 2; ++mi)
#pragma unroll
            for (int r = 0; r < 4; ++r) {
                float s = 0.f;
#pragma unroll
                for (int j = 0; j < 4; ++j) { float t = acc[j][mi][r]; s += t * t; }
                s += __shfl_xor(s, 1, 64);
                s += __shfl_xor(s, 2, 64);
                s += __shfl_xor(s, 4, 64);
                s += __shfl_xor(s, 8, 64);
                vacc[mi][r] = s;
            }
        if (cl == 0)
#pragma unroll
            for (int mi = 0; mi < 2; ++mi)
#pragma unroll
                for (int r = 0; r < 4; ++r)
                    vfp[wv * 32 + mi * 16 + q * 4 + r] = vacc[mi][r];
    }
    __syncthreads();
    if (tid < 32) {
        float v = vfb[tid] + qcp[0];
#pragma unroll
        for (int w = 0; w < 8; ++w) v += vfp[w * 32 + tid];
        vf[m0 + tid] = v;
    }
}

extern "C" void kernel_launch(void* const* d_in, const int* in_sizes, int n_in,
                              void* d_out, int out_size, void* d_ws, size_t ws_size,
                              hipStream_t stream) {
    const float* x  = (const float*)d_in[0];
    const float* w1 = (const float*)d_in[1];
    const float* b1 = (const float*)d_in[2];
    const float* w2 = (const float*)d_in[3];
    const float* lv = (const float*)d_in[4];
    const float* qb = (const float*)d_in[5];
    const float* qc = (const float*)d_in[6];

    char* ws = (char*)d_ws;
    __hip_bfloat16* ltf = (__hip_bfloat16*)(ws + OFF_LTF);
    __hip_bfloat16* w1f = (__hip_bfloat16*)(ws + OFF_W1F);
    __hip_bfloat16* w2f = (__hip_bfloat16*)(ws + OFF_W2F);

    float* pi = (float*)d_out;
    float* vf = pi + (size_t)B_ * OUT_;

    k_prep <<<172, 256, 0, stream>>>(w1, w2, lv, qb, w1f, w2f, ltf);
    k_fused<<<B_ / 32, 512, 0, stream>>>(x, w1f, b1, w2f, ltf, qc, pi, vf);
}